// Round 4
// baseline (339.922 us; speedup 1.0000x reference)
//
#include <hip/hip_runtime.h>

typedef unsigned short ushort_t;
typedef unsigned int uint32;

#define N_NODES 10000
#define N_EDGES 160000
#define ET (N_NODES + N_EDGES)   /* 170000 edges incl self-loops */
#define MPAD 10112               /* 79 * 128 */
#define HT 1024                  /* heads * hid */
#define HEADS 8
#define NEG 0.2f

/* ---- ws layout (bytes, 256-aligned) ---- */
#define O_FLAG     0             /* flags[0]=edge64, flags[1]=inputs_f32 */
#define O_SRC      256
#define O_DST      (O_SRC + 680192)
#define O_COUNTS   (O_DST + 680192)
#define O_OFFS     (O_COUNTS + 40192)
#define O_CURS     (O_OFFS + 40192)
#define O_SSORT    (O_CURS + 40192)
#define O_ALS      (O_SSORT + 680192)
#define O_ALD      (O_ALS + 320000)
#define O_AL3S     (O_ALD + 320000)
#define O_AL3D     (O_AL3S + 40192)
#define O_H3       (O_AL3D + 40192)
#define O_XF       (O_H3 + 160000)      /* x fp32: 140000 floats */
#define O_W1F      (O_XF + 560128)      /* 14336 floats */
#define O_AS1F     (O_W1F + 57344)      /* 6 x 1024 floats: as1,ad1,b1,as2,ad2,b2 */
#define O_W3F      (O_AS1F + 24576)     /* 4096 floats */
#define O_S3F      (O_W3F + 16384)      /* as3 @0, ad3 @+16 floats, b3 @+32 floats */
#define O_W2T      (O_S3F + 768)        /* bf16 [1024,1024] transposed */
#define O_BUFA     (O_W2T + 2097152)
#define O_BUFB     (O_BUFA + 20709376)

__device__ __forceinline__ float bf2f(ushort_t u){ return __uint_as_float(((uint32)u) << 16); }
__device__ __forceinline__ ushort_t f2bf(float f){
    uint32 x = __float_as_uint(f);
    return (ushort_t)((x + 0x7fffu + ((x >> 16) & 1u)) >> 16);
}
__device__ __forceinline__ void unpack2(uint32 u, float& lo, float& hi){
    lo = __uint_as_float(u << 16);
    hi = __uint_as_float(u & 0xffff0000u);
}

typedef __bf16 bf16x8 __attribute__((ext_vector_type(8)));
typedef float  f32x4  __attribute__((ext_vector_type(4)));

typedef const __attribute__((address_space(1))) uint32* gas1_u32;
typedef       __attribute__((address_space(3))) uint32* las3_u32;

__device__ __forceinline__ void gload_lds16(const void* g, void* l){
    __builtin_amdgcn_global_load_lds((gas1_u32)g, (las3_u32)l, 16, 0, 0);
}

/* inline dtype probes (see R1/R2 analysis): bf16 low-element exponent field
   concentrates near 127; fp32 low 16 bits are uniform mantissa bits. */
__device__ __forceinline__ int probe_f32(const uint32* __restrict__ w){
    int cnt = 0;
    for (int i = 0; i < 256; i++){
        uint32 e = (w[i] >> 7) & 0xffu;
        cnt += (e >= 64u && e <= 160u) ? 1 : 0;
    }
    return (cnt > 200) ? 0 : 1;
}
__device__ __forceinline__ int probe_edge64(const int* __restrict__ ei){
    int nz = 0;
    for (int i = 0; i < 128; i++) nz |= ei[2*i + 1];
    return (nz == 0) ? 1 : 0;
}

/* ---------------- k_setup: flags + all small-array conversions + counts-zero +
   W2 transpose, one dispatch. grid = (1024, 14). ---------------- */
struct CvtArgs {
    const void* src[12];
    float*      dst[12];
    int         n[12];
};

__global__ __launch_bounds__(256) void k_setup(CvtArgs a, const void* __restrict__ W2,
                                               const uint32* __restrict__ w1raw,
                                               const int* __restrict__ eiraw,
                                               int* __restrict__ counts,
                                               ushort_t* __restrict__ W2T,
                                               int* __restrict__ flags){
    __shared__ ushort_t tile[32][33];
    int slice = blockIdx.y;
    int tid = threadIdx.x;
    if (slice < 12){
        int n = a.n[slice];
        int base = blockIdx.x * 1024 + tid * 4;
        if (base >= n) return;
        int f32 = probe_f32(w1raw);
        const void* s = a.src[slice];
        float* d = a.dst[slice];
        #pragma unroll
        for (int j = 0; j < 4; j++){
            int i = base + j;
            if (i < n) d[i] = f32 ? ((const float*)s)[i] : bf2f(((const ushort_t*)s)[i]);
        }
    } else if (slice == 12){
        /* zero counts; block x==10 also publishes flags */
        if (blockIdx.x == 10){
            if (tid == 0) flags[0] = probe_edge64(eiraw);
            if (tid == 1) flags[1] = probe_f32(w1raw);
            return;
        }
        if (blockIdx.x < 10){
            int i0 = blockIdx.x * 1024 + tid * 4;
            if (i0 + 3 < N_NODES){
                *(int4*)(counts + i0) = make_int4(0,0,0,0);
            } else {
                for (int j = 0; j < 4; j++) if (i0 + j < N_NODES) counts[i0 + j] = 0;
            }
        }
    } else {
        /* W2 transpose -> bf16 [N,K] */
        int f32 = probe_f32(w1raw);
        int bx = blockIdx.x & 31, by = blockIdx.x >> 5;
        int cx = tid & 31;
        int ry = (tid >> 5) * 4;
        #pragma unroll
        for (int r = 0; r < 4; r++){
            size_t idx = (size_t)(by*32 + ry + r)*1024 + bx*32 + cx;
            tile[ry + r][cx] = f32 ? f2bf(((const float*)W2)[idx]) : ((const ushort_t*)W2)[idx];
        }
        __syncthreads();
        #pragma unroll
        for (int r = 0; r < 4; r++)
            W2T[(size_t)(bx*32 + ry + r)*1024 + by*32 + cx] = tile[cx][ry + r];
    }
}

/* ---------------- extract edges (+self-loops) as int32, fused histogram ---------------- */
__global__ __launch_bounds__(256) void k_extract_hist(const void* __restrict__ ei, const int* __restrict__ flags,
                                                      int* __restrict__ src, int* __restrict__ dst,
                                                      int* __restrict__ counts){
    int i = blockIdx.x * 256 + threadIdx.x;
    int is64 = flags[0];
    int s = -1, d = -1;
    if (i < N_EDGES){
        if (is64){
            const long long* p = (const long long*)ei;
            s = (int)p[i]; d = (int)p[N_EDGES + i];
        } else {
            const int* p = (const int*)ei;
            s = p[i]; d = p[N_EDGES + i];
        }
    } else if (i < ET){
        s = i - N_EDGES; d = s;
    }
    if (d >= 0){
        src[i] = s; dst[i] = d;
        atomicAdd(&counts[d], 1);
    }
}

/* single-block exclusive scan over N_NODES counts -> offs + cursors */
__global__ __launch_bounds__(1024) void k_scan(const int* __restrict__ counts, int* __restrict__ offs,
                                               int* __restrict__ cursors, int n){
    __shared__ int wsum[16];
    __shared__ int running_s;
    int tid = threadIdx.x;
    int lane = tid & 63, wid = tid >> 6;
    if (tid == 0) running_s = 0;
    __syncthreads();
    for (int base = 0; base < n; base += 1024){
        int i = base + tid;
        int v = (i < n) ? counts[i] : 0;
        int x = v;
        #pragma unroll
        for (int d = 1; d < 64; d <<= 1){
            int t = __shfl_up(x, d, 64);
            if (lane >= d) x += t;
        }
        if (lane == 63) wsum[wid] = x;
        __syncthreads();
        if (wid == 0 && lane < 16){
            int w = wsum[lane];
            #pragma unroll
            for (int d = 1; d < 16; d <<= 1){
                int t = __shfl_up(w, d, 64);
                if (lane >= d) w += t;
            }
            wsum[lane] = w;
        }
        __syncthreads();
        int wprefix = (wid == 0) ? 0 : wsum[wid - 1];
        int run = running_s;
        int excl = run + wprefix + (x - v);
        if (i < n){ offs[i] = excl; cursors[i] = excl; }
        __syncthreads();
        if (tid == 0) running_s = run + wsum[15];
        __syncthreads();
    }
    if (tid == 0) offs[n] = running_s;
}

__global__ __launch_bounds__(256) void k_scatter(const int* __restrict__ src, const int* __restrict__ dst,
                                                 int* __restrict__ cursors, int* __restrict__ ssort){
    int i = blockIdx.x * 256 + threadIdx.x;
    if (i < ET){
        int pos = atomicAdd(&cursors[dst[i]], 1);
        ssort[pos] = src[i];
    }
}

/* ---------------- layer-1 GEMM fused with attention dots ---------------- */
__global__ __launch_bounds__(256) void k_gemm1f(const float* __restrict__ x, const float* __restrict__ W1,
                                                const float* __restrict__ a_src, const float* __restrict__ a_dst,
                                                ushort_t* __restrict__ h1,
                                                float* __restrict__ alS, float* __restrict__ alD){
    __shared__ float w1s[14 * HT];
    int tid = threadIdx.x;
    for (int i = tid * 4; i < 14 * HT; i += 1024)
        *(float4*)(w1s + i) = *(const float4*)(W1 + i);
    int c0 = tid * 4;
    float4 sv = *(const float4*)(a_src + c0);
    float4 dv = *(const float4*)(a_dst + c0);
    int head = tid >> 5, l32 = tid & 31;
    __syncthreads();
    for (int n = blockIdx.x; n < N_NODES; n += gridDim.x){
        float a0=0.f, a1=0.f, a2=0.f, a3=0.f;
        #pragma unroll
        for (int k = 0; k < 14; k++){
            float xv = x[n*14 + k];
            float4 w = *(const float4*)(w1s + k*HT + c0);
            a0 += xv*w.x; a1 += xv*w.y; a2 += xv*w.z; a3 += xv*w.w;
        }
        uint2 o;
        o.x = (uint32)f2bf(a0) | ((uint32)f2bf(a1) << 16);
        o.y = (uint32)f2bf(a2) | ((uint32)f2bf(a3) << 16);
        *(uint2*)(h1 + (size_t)n*HT + c0) = o;
        float h0,h1v,h2,h3v;
        unpack2(o.x, h0, h1v); unpack2(o.y, h2, h3v);
        float s = h0*sv.x + h1v*sv.y + h2*sv.z + h3v*sv.w;
        float d = h0*dv.x + h1v*dv.y + h2*dv.z + h3v*dv.w;
        #pragma unroll
        for (int of = 16; of; of >>= 1){ s += __shfl_xor(s, of, 32); d += __shfl_xor(d, of, 32); }
        if (l32 == 0){ alS[n*HEADS + head] = s; alD[n*HEADS + head] = d; }
    }
}

/* ---------------- fused segment-softmax + aggregate + bias + relu (v3) ----------------
   Barrier-free: 2 nodes/block, 2 waves/node; lane owns 8 channels so each head
   lives entirely inside one wave. Edge ids broadcast via shuffles; online softmax. */
__global__ __launch_bounds__(256) void k_gat_agg(const ushort_t* __restrict__ H, const float* __restrict__ alS,
                                                 const float* __restrict__ alD, const int* __restrict__ offs,
                                                 const int* __restrict__ srcs, const float* __restrict__ bias,
                                                 ushort_t* __restrict__ out){
    int tid = threadIdx.x;
    int wv = tid >> 6, lane = tid & 63;
    int n = blockIdx.x * 2 + (wv >> 1);
    int half = wv & 1;
    int beg = offs[n], end = offs[n+1];
    int head = half*4 + (lane >> 4);
    int slot = lane & 15;
    float ad = alD[n*HEADS + head];

    /* online softmax stats per (head, slot), then 4-step butterfly over slots */
    float m = -1e30f, z = 0.f;
    for (int c = beg; c < end; c += 64){
        int cn = min(64, end - c);
        int sreg = (lane < cn) ? srcs[c + lane] : 0;
        for (int p = slot; p < cn; p += 16){
            int s = __shfl(sreg, p, 64);
            float v = alS[s*HEADS + head] + ad;
            v = v > 0.f ? v : NEG*v;
            if (v > m){ z = z*__expf(m - v) + 1.f; m = v; }
            else z += __expf(v - m);
        }
    }
    #pragma unroll
    for (int o = 1; o < 16; o <<= 1){
        float m2 = __shfl_xor(m, o, 64);
        float z2 = __shfl_xor(z, o, 64);
        float nm = fmaxf(m, m2);
        z = z*__expf(m - nm) + z2*__expf(m2 - nm);
        m = nm;
    }
    float inv = 1.f / (z + 1e-16f);

    int ch0 = half*512 + lane*8;
    const ushort_t* Hc = H + ch0;
    float c0=0.f,c1=0.f,c2=0.f,c3=0.f,c4=0.f,c5=0.f,c6=0.f,c7=0.f;
    for (int c = beg; c < end; c += 64){
        int cn = min(64, end - c);
        int sreg = (lane < cn) ? srcs[c + lane] : 0;
        int j = 0;
        for (; j + 2 <= cn; j += 2){
            int s0 = __shfl(sreg, j, 64);
            int s1 = __shfl(sreg, j+1, 64);
            uint4 u0 = *(const uint4*)(Hc + (size_t)s0*HT);
            uint4 u1 = *(const uint4*)(Hc + (size_t)s1*HT);
            float v0 = alS[s0*HEADS + head] + ad;
            float v1 = alS[s1*HEADS + head] + ad;
            v0 = v0 > 0.f ? v0 : NEG*v0;
            v1 = v1 > 0.f ? v1 : NEG*v1;
            float w0 = __expf(v0 - m) * inv;
            float w1 = __expf(v1 - m) * inv;
            float f0,f1,f2,f3,f4,f5,f6,f7;
            unpack2(u0.x,f0,f1); unpack2(u0.y,f2,f3); unpack2(u0.z,f4,f5); unpack2(u0.w,f6,f7);
            c0+=w0*f0; c1+=w0*f1; c2+=w0*f2; c3+=w0*f3;
            c4+=w0*f4; c5+=w0*f5; c6+=w0*f6; c7+=w0*f7;
            unpack2(u1.x,f0,f1); unpack2(u1.y,f2,f3); unpack2(u1.z,f4,f5); unpack2(u1.w,f6,f7);
            c0+=w1*f0; c1+=w1*f1; c2+=w1*f2; c3+=w1*f3;
            c4+=w1*f4; c5+=w1*f5; c6+=w1*f6; c7+=w1*f7;
        }
        if (j < cn){
            int s0 = __shfl(sreg, j, 64);
            uint4 u0 = *(const uint4*)(Hc + (size_t)s0*HT);
            float v0 = alS[s0*HEADS + head] + ad;
            v0 = v0 > 0.f ? v0 : NEG*v0;
            float w0 = __expf(v0 - m) * inv;
            float f0,f1,f2,f3,f4,f5,f6,f7;
            unpack2(u0.x,f0,f1); unpack2(u0.y,f2,f3); unpack2(u0.z,f4,f5); unpack2(u0.w,f6,f7);
            c0+=w0*f0; c1+=w0*f1; c2+=w0*f2; c3+=w0*f3;
            c4+=w0*f4; c5+=w0*f5; c6+=w0*f6; c7+=w0*f7;
        }
    }
    float4 b0 = *(const float4*)(bias + ch0);
    float4 b1 = *(const float4*)(bias + ch0 + 4);
    c0 = fmaxf(c0+b0.x, 0.f); c1 = fmaxf(c1+b0.y, 0.f);
    c2 = fmaxf(c2+b0.z, 0.f); c3 = fmaxf(c3+b0.w, 0.f);
    c4 = fmaxf(c4+b1.x, 0.f); c5 = fmaxf(c5+b1.y, 0.f);
    c6 = fmaxf(c6+b1.z, 0.f); c7 = fmaxf(c7+b1.w, 0.f);
    uint4 o;
    o.x = (uint32)f2bf(c0) | ((uint32)f2bf(c1) << 16);
    o.y = (uint32)f2bf(c2) | ((uint32)f2bf(c3) << 16);
    o.z = (uint32)f2bf(c4) | ((uint32)f2bf(c5) << 16);
    o.w = (uint32)f2bf(c6) | ((uint32)f2bf(c7) << 16);
    *(uint4*)(out + (size_t)n*HT + ch0) = o;
}

/* ---------------- layer-2 GEMM: bf16 MFMA, fused attention dots ----------------
   Block (bm,bn): rows bm*128..+128, cols bn*128..+128 == head bn exactly,
   so the epilogue computes complete alS/alD for head bn of these rows. */
__global__ __launch_bounds__(256) void k_gemm2(const ushort_t* __restrict__ A, const ushort_t* __restrict__ BT,
                                               ushort_t* __restrict__ C,
                                               const float* __restrict__ aS, const float* __restrict__ aD,
                                               float* __restrict__ alS, float* __restrict__ alD){
    __shared__ ushort_t lA[128*32];
    __shared__ ushort_t lB[128*32];
    __shared__ float reds[2][64][2];
    int tid = threadIdx.x;
    int bm = blockIdx.x, bn = blockIdx.y;
    int lane = tid & 63;
    int wave = tid >> 6;
    int wm = (wave & 1) * 64, wn = (wave >> 1) * 64;
    int lm = lane & 15, kg = lane >> 4;
    f32x4 acc[4][4];
    #pragma unroll
    for (int i = 0; i < 4; i++)
        #pragma unroll
        for (int j = 0; j < 4; j++) acc[i][j] = (f32x4)0.0f;

    const int K = 1024;
    int rowA0 = bm * 128, rowB0 = bn * 128;
    for (int k0 = 0; k0 < K; k0 += 32){
        #pragma unroll
        for (int it = 0; it < 2; ++it){
            int s = tid + it*256;
            int r = s >> 2, ks = s & 3;
            gload_lds16(A  + (size_t)(rowA0 + r)*K + k0 + ks*8, lA + s*8);
            gload_lds16(BT + (size_t)(rowB0 + r)*K + k0 + ks*8, lB + s*8);
        }
        __syncthreads();
        bf16x8 af[4], bfr[4];
        #pragma unroll
        for (int mt = 0; mt < 4; mt++) af[mt]  = *(const bf16x8*)(lA + (wm + mt*16 + lm)*32 + kg*8);
        #pragma unroll
        for (int nt = 0; nt < 4; nt++) bfr[nt] = *(const bf16x8*)(lB + (wn + nt*16 + lm)*32 + kg*8);
        #pragma unroll
        for (int mt = 0; mt < 4; mt++)
            #pragma unroll
            for (int nt = 0; nt < 4; nt++)
                acc[mt][nt] = __builtin_amdgcn_mfma_f32_16x16x32_bf16(af[mt], bfr[nt], acc[mt][nt], 0, 0, 0);
        __syncthreads();
    }
    #pragma unroll
    for (int mt = 0; mt < 4; mt++){
        int row_base = bm*128 + wm + mt*16 + kg*4;
        #pragma unroll
        for (int nt = 0; nt < 4; nt++){
            int col = bn*128 + wn + nt*16 + lm;
            #pragma unroll
            for (int r = 0; r < 4; r++){
                int row = row_base + r;
                if (row < N_NODES) C[(size_t)row*HT + col] = f2bf(acc[mt][nt][r]);
            }
        }
    }
    /* fused attention-dot epilogue for head bn */
    float as_l[4], ad_l[4];
    #pragma unroll
    for (int nt = 0; nt < 4; nt++){
        as_l[nt] = aS[bn*128 + wn + nt*16 + lm];
        ad_l[nt] = aD[bn*128 + wn + nt*16 + lm];
    }
    float psA[4][4], pdA[4][4];
    #pragma unroll
    for (int mt = 0; mt < 4; mt++){
        #pragma unroll
        for (int r = 0; r < 4; r++){
            float ps = acc[mt][0][r]*as_l[0] + acc[mt][1][r]*as_l[1]
                     + acc[mt][2][r]*as_l[2] + acc[mt][3][r]*as_l[3];
            float pd = acc[mt][0][r]*ad_l[0] + acc[mt][1][r]*ad_l[1]
                     + acc[mt][2][r]*ad_l[2] + acc[mt][3][r]*ad_l[3];
            #pragma unroll
            for (int o = 1; o < 16; o <<= 1){ ps += __shfl_xor(ps, o, 64); pd += __shfl_xor(pd, o, 64); }
            psA[mt][r] = ps; pdA[mt][r] = pd;
            if (wn == 64 && lm == 0){
                int rl = mt*16 + kg*4 + r;
                reds[wm >> 6][rl][0] = ps;
                reds[wm >> 6][rl][1] = pd;
            }
        }
    }
    __syncthreads();
    if (wn == 0 && lm == 0){
        #pragma unroll
        for (int mt = 0; mt < 4; mt++){
            #pragma unroll
            for (int r = 0; r < 4; r++){
                int rl = mt*16 + kg*4 + r;
                int row = bm*128 + wm + rl;
                if (row < N_NODES){
                    alS[row*HEADS + bn] = psA[mt][r] + reds[wm >> 6][rl][0];
                    alD[row*HEADS + bn] = pdA[mt][r] + reds[wm >> 6][rl][1];
                }
            }
        }
    }
}

/* ---------------- layer-3 GEMM: wave-per-node, W3 in registers ---------------- */
__global__ __launch_bounds__(256) void k_gemm3(const ushort_t* __restrict__ A, const float* __restrict__ W3,
                                               const float* __restrict__ s3,
                                               float* __restrict__ h3, float* __restrict__ al3s, float* __restrict__ al3d){
    int tid = threadIdx.x;
    int lane = tid & 63, wave = tid >> 6;
    int n = blockIdx.x * 4 + wave;
    if (n >= N_NODES) return;
    float4 w3r[16];
    #pragma unroll
    for (int j = 0; j < 16; j++) w3r[j] = ((const float4*)W3)[lane*16 + j];
    const uint4* ap = (const uint4*)(A + (size_t)n*HT + lane*16);
    uint4 u0 = ap[0], u1 = ap[1];
    uint32 uu[8] = {u0.x,u0.y,u0.z,u0.w,u1.x,u1.y,u1.z,u1.w};
    float acc0=0.f, acc1=0.f, acc2=0.f, acc3=0.f;
    #pragma unroll
    for (int p = 0; p < 8; p++){
        float lo, hi;
        unpack2(uu[p], lo, hi);
        float4 wl = w3r[p*2], wh = w3r[p*2+1];
        acc0 += lo*wl.x + hi*wh.x;
        acc1 += lo*wl.y + hi*wh.y;
        acc2 += lo*wl.z + hi*wh.z;
        acc3 += lo*wl.w + hi*wh.w;
    }
    #pragma unroll
    for (int o = 32; o; o >>= 1){
        acc0 += __shfl_xor(acc0, o, 64); acc1 += __shfl_xor(acc1, o, 64);
        acc2 += __shfl_xor(acc2, o, 64); acc3 += __shfl_xor(acc3, o, 64);
    }
    if (lane == 0){
        *(float4*)(h3 + n*4) = make_float4(acc0, acc1, acc2, acc3);
        al3s[n] = acc0*s3[0] + acc1*s3[1] + acc2*s3[2] + acc3*s3[3];
        al3d[n] = acc0*s3[16] + acc1*s3[17] + acc2*s3[18] + acc3*s3[19];
    }
}

/* ---------------- layer-3 attention aggregate: wave-per-node ---------------- */
__global__ __launch_bounds__(256) void k_gat_agg3(const float* __restrict__ h3, const float* __restrict__ al3s,
                                                  const float* __restrict__ al3d, const int* __restrict__ offs,
                                                  const int* __restrict__ srcs, const float* __restrict__ b3,
                                                  const int* __restrict__ flags, void* __restrict__ out){
    int tid = threadIdx.x;
    int l = tid & 63, wave = tid >> 6;
    int n = blockIdx.x * 4 + wave;
    if (n >= N_NODES) return;
    int beg = offs[n], end = offs[n+1];
    float ad = al3d[n];
    float m = -1e30f;
    for (int e = beg + l; e < end; e += 64){
        float v = al3s[srcs[e]] + ad; v = v > 0.f ? v : NEG*v;
        m = fmaxf(m, v);
    }
    #pragma unroll
    for (int o = 32; o; o >>= 1) m = fmaxf(m, __shfl_xor(m, o, 64));
    float z = 0.f;
    for (int e = beg + l; e < end; e += 64){
        float v = al3s[srcs[e]] + ad; v = v > 0.f ? v : NEG*v;
        z += __expf(v - m);
    }
    #pragma unroll
    for (int o = 32; o; o >>= 1) z += __shfl_xor(z, o, 64);
    float inv = 1.f / (z + 1e-16f);
    float a0=0.f, a1=0.f, a2=0.f, a3=0.f;
    for (int e = beg + l; e < end; e += 64){
        int s = srcs[e];
        float v = al3s[s] + ad; v = v > 0.f ? v : NEG*v;
        float w = __expf(v - m) * inv;
        float4 hv = *(const float4*)(h3 + s*4);
        a0 += w*hv.x; a1 += w*hv.y; a2 += w*hv.z; a3 += w*hv.w;
    }
    #pragma unroll
    for (int o = 32; o; o >>= 1){
        a0 += __shfl_xor(a0, o, 64); a1 += __shfl_xor(a1, o, 64);
        a2 += __shfl_xor(a2, o, 64); a3 += __shfl_xor(a3, o, 64);
    }
    if (l == 0){
        float r0 = fmaxf(a0 + b3[0], 0.f);
        float r1 = fmaxf(a1 + b3[1], 0.f);
        float r2 = fmaxf(a2 + b3[2], 0.f);
        float r3 = fmaxf(a3 + b3[3], 0.f);
        if (flags[1]){
            float* o4 = (float*)out;
            o4[n*4+0]=r0; o4[n*4+1]=r1; o4[n*4+2]=r2; o4[n*4+3]=r3;
        } else {
            ushort_t* o2 = (ushort_t*)out;
            o2[n*4+0]=f2bf(r0); o2[n*4+1]=f2bf(r1); o2[n*4+2]=f2bf(r2); o2[n*4+3]=f2bf(r3);
        }
    }
}

extern "C" void kernel_launch(void* const* d_in, const int* in_sizes, int n_in,
                              void* d_out, int out_size, void* d_ws, size_t ws_size,
                              hipStream_t stream){
    const void* x   = d_in[0];
    const void* ei  = d_in[1];
    const void* W1  = d_in[2];
    const void* as1 = d_in[3];
    const void* ad1 = d_in[4];
    const void* b1  = d_in[5];
    const void* W2  = d_in[6];
    const void* as2 = d_in[7];
    const void* ad2 = d_in[8];
    const void* b2  = d_in[9];
    const void* W3  = d_in[10];
    const void* as3 = d_in[11];
    const void* ad3 = d_in[12];
    const void* b3  = d_in[13];

    char* ws = (char*)d_ws;
    int* flags     = (int*)(ws + O_FLAG);
    int* srcA      = (int*)(ws + O_SRC);
    int* dstA      = (int*)(ws + O_DST);
    int* counts    = (int*)(ws + O_COUNTS);
    int* offs      = (int*)(ws + O_OFFS);
    int* cursors   = (int*)(ws + O_CURS);
    int* ssort     = (int*)(ws + O_SSORT);
    float* alS     = (float*)(ws + O_ALS);
    float* alD     = (float*)(ws + O_ALD);
    float* al3s    = (float*)(ws + O_AL3S);
    float* al3d    = (float*)(ws + O_AL3D);
    float* h3      = (float*)(ws + O_H3);
    float* xF      = (float*)(ws + O_XF);
    float* W1F     = (float*)(ws + O_W1F);
    float* wvecF   = (float*)(ws + O_AS1F);
    float* W3F     = (float*)(ws + O_W3F);
    float* s3F     = (float*)(ws + O_S3F);
    ushort_t* W2T  = (ushort_t*)(ws + O_W2T);
    ushort_t* bufA = (ushort_t*)(ws + O_BUFA);
    ushort_t* bufB = (ushort_t*)(ws + O_BUFB);

    const int EB = (ET + 255) / 256;

    CvtArgs ca;
    ca.src[0]=x;   ca.dst[0]=xF;            ca.n[0]=140000;
    ca.src[1]=W1;  ca.dst[1]=W1F;           ca.n[1]=14336;
    ca.src[2]=as1; ca.dst[2]=wvecF+0*1024;  ca.n[2]=1024;
    ca.src[3]=ad1; ca.dst[3]=wvecF+1*1024;  ca.n[3]=1024;
    ca.src[4]=b1;  ca.dst[4]=wvecF+2*1024;  ca.n[4]=1024;
    ca.src[5]=as2; ca.dst[5]=wvecF+3*1024;  ca.n[5]=1024;
    ca.src[6]=ad2; ca.dst[6]=wvecF+4*1024;  ca.n[6]=1024;
    ca.src[7]=b2;  ca.dst[7]=wvecF+5*1024;  ca.n[7]=1024;
    ca.src[8]=W3;  ca.dst[8]=W3F;           ca.n[8]=4096;
    ca.src[9]=as3; ca.dst[9]=s3F+0;         ca.n[9]=4;
    ca.src[10]=ad3; ca.dst[10]=s3F+16;      ca.n[10]=4;
    ca.src[11]=b3;  ca.dst[11]=s3F+32;      ca.n[11]=4;

    k_setup<<<dim3(1024, 14), 256, 0, stream>>>(ca, W2, (const uint32*)W1, (const int*)ei,
                                                counts, W2T, flags);
    k_extract_hist<<<EB, 256, 0, stream>>>(ei, flags, srcA, dstA, counts);
    k_scan<<<1, 1024, 0, stream>>>(counts, offs, cursors, N_NODES);
    k_scatter<<<EB, 256, 0, stream>>>(srcA, dstA, cursors, ssort);

    /* layer 1 (gemm + dots fused) */
    k_gemm1f<<<512, 256, 0, stream>>>(xF, W1F, wvecF+0*1024, wvecF+1*1024, bufA, alS, alD);
    k_gat_agg<<<5000, 256, 0, stream>>>(bufA, alS, alD, offs, ssort, wvecF+2*1024, bufB);

    /* layer 2 (gemm + dots fused) */
    k_gemm2<<<dim3(79, 8), 256, 0, stream>>>(bufB, W2T, bufA, wvecF+3*1024, wvecF+4*1024, alS, alD);
    k_gat_agg<<<5000, 256, 0, stream>>>(bufA, alS, alD, offs, ssort, wvecF+5*1024, bufB);

    /* layer 3 */
    k_gemm3<<<2500, 256, 0, stream>>>(bufB, W3F, s3F, h3, al3s, al3d);
    k_gat_agg3<<<2500, 256, 0, stream>>>(h3, al3s, al3d, offs, ssort, s3F+32, flags, d_out);
}

// Round 5
// 330.636 us; speedup vs baseline: 1.0281x; 1.0281x over previous
//
#include <hip/hip_runtime.h>

typedef unsigned short ushort_t;
typedef unsigned int uint32;

#define N_NODES 10000
#define N_EDGES 160000
#define ET (N_NODES + N_EDGES)   /* 170000 edges incl self-loops */
#define MPAD 10112               /* 79 * 128 */
#define HT 1024                  /* heads * hid */
#define HEADS 8
#define NEG 0.2f

/* ---- ws layout (bytes, 256-aligned) ---- */
#define O_FLAG     0             /* flags[0]=edge64, flags[1]=inputs_f32 */
#define O_SRC      256
#define O_DST      (O_SRC + 680192)
#define O_COUNTS   (O_DST + 680192)
#define O_OFFS     (O_COUNTS + 40192)
#define O_CURS     (O_OFFS + 40192)
#define O_SSORT    (O_CURS + 40192)
#define O_ALS      (O_SSORT + 680192)
#define O_ALD      (O_ALS + 320000)
#define O_AL3S     (O_ALD + 320000)
#define O_AL3D     (O_AL3S + 40192)
#define O_H3       (O_AL3D + 40192)
#define O_XF       (O_H3 + 160000)      /* x fp32: 140000 floats */
#define O_W1F      (O_XF + 560128)      /* 14336 floats */
#define O_AS1F     (O_W1F + 57344)      /* 6 x 1024 floats: as1,ad1,b1,as2,ad2,b2 */
#define O_W3F      (O_AS1F + 24576)     /* 4096 floats */
#define O_S3F      (O_W3F + 16384)      /* as3 @0, ad3 @+16 floats, b3 @+32 floats */
#define O_W2T      (O_S3F + 768)        /* bf16 [1024,1024] transposed */
#define O_BUFA     (O_W2T + 2097152)
#define O_BUFB     (O_BUFA + 20709376)

__device__ __forceinline__ float bf2f(ushort_t u){ return __uint_as_float(((uint32)u) << 16); }
__device__ __forceinline__ ushort_t f2bf(float f){
    uint32 x = __float_as_uint(f);
    return (ushort_t)((x + 0x7fffu + ((x >> 16) & 1u)) >> 16);
}
__device__ __forceinline__ void unpack2(uint32 u, float& lo, float& hi){
    lo = __uint_as_float(u << 16);
    hi = __uint_as_float(u & 0xffff0000u);
}

typedef __bf16 bf16x8 __attribute__((ext_vector_type(8)));
typedef float  f32x4  __attribute__((ext_vector_type(4)));

typedef const __attribute__((address_space(1))) uint32* gas1_u32;
typedef       __attribute__((address_space(3))) uint32* las3_u32;

__device__ __forceinline__ void gload_lds16(const void* g, void* l){
    __builtin_amdgcn_global_load_lds((gas1_u32)g, (las3_u32)l, 16, 0, 0);
}

/* inline dtype probes (see R1/R2 analysis): bf16 low-element exponent field
   concentrates near 127; fp32 low 16 bits are uniform mantissa bits. */
__device__ __forceinline__ int probe_f32(const uint32* __restrict__ w){
    int cnt = 0;
    for (int i = 0; i < 256; i++){
        uint32 e = (w[i] >> 7) & 0xffu;
        cnt += (e >= 64u && e <= 160u) ? 1 : 0;
    }
    return (cnt > 200) ? 0 : 1;
}
__device__ __forceinline__ int probe_edge64(const int* __restrict__ ei){
    int nz = 0;
    for (int i = 0; i < 128; i++) nz |= ei[2*i + 1];
    return (nz == 0) ? 1 : 0;
}

/* ---------------- k_setup ---------------- */
struct CvtArgs {
    const void* src[12];
    float*      dst[12];
    int         n[12];
};

__global__ __launch_bounds__(256) void k_setup(CvtArgs a, const void* __restrict__ W2,
                                               const uint32* __restrict__ w1raw,
                                               const int* __restrict__ eiraw,
                                               int* __restrict__ counts,
                                               ushort_t* __restrict__ W2T,
                                               int* __restrict__ flags){
    __shared__ ushort_t tile[32][33];
    int slice = blockIdx.y;
    int tid = threadIdx.x;
    if (slice < 12){
        int n = a.n[slice];
        int base = blockIdx.x * 1024 + tid * 4;
        if (base >= n) return;
        int f32 = probe_f32(w1raw);
        const void* s = a.src[slice];
        float* d = a.dst[slice];
        #pragma unroll
        for (int j = 0; j < 4; j++){
            int i = base + j;
            if (i < n) d[i] = f32 ? ((const float*)s)[i] : bf2f(((const ushort_t*)s)[i]);
        }
    } else if (slice == 12){
        if (blockIdx.x == 10){
            if (tid == 0) flags[0] = probe_edge64(eiraw);
            if (tid == 1) flags[1] = probe_f32(w1raw);
            return;
        }
        if (blockIdx.x < 10){
            int i0 = blockIdx.x * 1024 + tid * 4;
            if (i0 + 3 < N_NODES){
                *(int4*)(counts + i0) = make_int4(0,0,0,0);
            } else {
                for (int j = 0; j < 4; j++) if (i0 + j < N_NODES) counts[i0 + j] = 0;
            }
        }
    } else {
        int f32 = probe_f32(w1raw);
        int bx = blockIdx.x & 31, by = blockIdx.x >> 5;
        int cx = tid & 31;
        int ry = (tid >> 5) * 4;
        #pragma unroll
        for (int r = 0; r < 4; r++){
            size_t idx = (size_t)(by*32 + ry + r)*1024 + bx*32 + cx;
            tile[ry + r][cx] = f32 ? f2bf(((const float*)W2)[idx]) : ((const ushort_t*)W2)[idx];
        }
        __syncthreads();
        #pragma unroll
        for (int r = 0; r < 4; r++)
            W2T[(size_t)(bx*32 + ry + r)*1024 + by*32 + cx] = tile[cx][ry + r];
    }
}

/* ---------------- extract edges (+self-loops) as int32, fused histogram ---------------- */
__global__ __launch_bounds__(256) void k_extract_hist(const void* __restrict__ ei, const int* __restrict__ flags,
                                                      int* __restrict__ src, int* __restrict__ dst,
                                                      int* __restrict__ counts){
    int i = blockIdx.x * 256 + threadIdx.x;
    int is64 = flags[0];
    int s = -1, d = -1;
    if (i < N_EDGES){
        if (is64){
            const long long* p = (const long long*)ei;
            s = (int)p[i]; d = (int)p[N_EDGES + i];
        } else {
            const int* p = (const int*)ei;
            s = p[i]; d = p[N_EDGES + i];
        }
    } else if (i < ET){
        s = i - N_EDGES; d = s;
    }
    if (d >= 0){
        src[i] = s; dst[i] = d;
        atomicAdd(&counts[d], 1);
    }
}

/* single-block exclusive scan over N_NODES counts -> offs + cursors */
__global__ __launch_bounds__(1024) void k_scan(const int* __restrict__ counts, int* __restrict__ offs,
                                               int* __restrict__ cursors, int n){
    __shared__ int wsum[16];
    __shared__ int running_s;
    int tid = threadIdx.x;
    int lane = tid & 63, wid = tid >> 6;
    if (tid == 0) running_s = 0;
    __syncthreads();
    for (int base = 0; base < n; base += 1024){
        int i = base + tid;
        int v = (i < n) ? counts[i] : 0;
        int x = v;
        #pragma unroll
        for (int d = 1; d < 64; d <<= 1){
            int t = __shfl_up(x, d, 64);
            if (lane >= d) x += t;
        }
        if (lane == 63) wsum[wid] = x;
        __syncthreads();
        if (wid == 0 && lane < 16){
            int w = wsum[lane];
            #pragma unroll
            for (int d = 1; d < 16; d <<= 1){
                int t = __shfl_up(w, d, 64);
                if (lane >= d) w += t;
            }
            wsum[lane] = w;
        }
        __syncthreads();
        int wprefix = (wid == 0) ? 0 : wsum[wid - 1];
        int run = running_s;
        int excl = run + wprefix + (x - v);
        if (i < n){ offs[i] = excl; cursors[i] = excl; }
        __syncthreads();
        if (tid == 0) running_s = run + wsum[15];
        __syncthreads();
    }
    if (tid == 0) offs[n] = running_s;
}

__global__ __launch_bounds__(256) void k_scatter(const int* __restrict__ src, const int* __restrict__ dst,
                                                 int* __restrict__ cursors, int* __restrict__ ssort){
    int i = blockIdx.x * 256 + threadIdx.x;
    if (i < ET){
        int pos = atomicAdd(&cursors[dst[i]], 1);
        ssort[pos] = src[i];
    }
}

/* ---------------- layer-1 GEMM fused with attention dots ---------------- */
__global__ __launch_bounds__(256) void k_gemm1f(const float* __restrict__ x, const float* __restrict__ W1,
                                                const float* __restrict__ a_src, const float* __restrict__ a_dst,
                                                ushort_t* __restrict__ h1,
                                                float* __restrict__ alS, float* __restrict__ alD){
    __shared__ float w1s[14 * HT];
    int tid = threadIdx.x;
    for (int i = tid * 4; i < 14 * HT; i += 1024)
        *(float4*)(w1s + i) = *(const float4*)(W1 + i);
    int c0 = tid * 4;
    float4 sv = *(const float4*)(a_src + c0);
    float4 dv = *(const float4*)(a_dst + c0);
    int head = tid >> 5, l32 = tid & 31;
    __syncthreads();
    for (int n = blockIdx.x; n < N_NODES; n += gridDim.x){
        float a0=0.f, a1=0.f, a2=0.f, a3=0.f;
        #pragma unroll
        for (int k = 0; k < 14; k++){
            float xv = x[n*14 + k];
            float4 w = *(const float4*)(w1s + k*HT + c0);
            a0 += xv*w.x; a1 += xv*w.y; a2 += xv*w.z; a3 += xv*w.w;
        }
        uint2 o;
        o.x = (uint32)f2bf(a0) | ((uint32)f2bf(a1) << 16);
        o.y = (uint32)f2bf(a2) | ((uint32)f2bf(a3) << 16);
        *(uint2*)(h1 + (size_t)n*HT + c0) = o;
        float h0,h1v,h2,h3v;
        unpack2(o.x, h0, h1v); unpack2(o.y, h2, h3v);
        float s = h0*sv.x + h1v*sv.y + h2*sv.z + h3v*sv.w;
        float d = h0*dv.x + h1v*dv.y + h2*dv.z + h3v*dv.w;
        #pragma unroll
        for (int of = 16; of; of >>= 1){ s += __shfl_xor(s, of, 32); d += __shfl_xor(d, of, 32); }
        if (l32 == 0){ alS[n*HEADS + head] = s; alD[n*HEADS + head] = d; }
    }
}

/* ---------------- fused segment-softmax + aggregate + bias + relu (v3.1) ----------------
   Barrier-free: 2 nodes/block, 2 waves/node; lane owns 8 channels.
   Phase-2 unrolled x4 for gather-latency hiding. */
__global__ __launch_bounds__(256) void k_gat_agg(const ushort_t* __restrict__ H, const float* __restrict__ alS,
                                                 const float* __restrict__ alD, const int* __restrict__ offs,
                                                 const int* __restrict__ srcs, const float* __restrict__ bias,
                                                 ushort_t* __restrict__ out){
    int tid = threadIdx.x;
    int wv = tid >> 6, lane = tid & 63;
    int n = blockIdx.x * 2 + (wv >> 1);
    int half = wv & 1;
    int beg = offs[n], end = offs[n+1];
    int head = half*4 + (lane >> 4);
    int slot = lane & 15;
    float ad = alD[n*HEADS + head];

    /* online softmax stats per (head, slot), then 4-step butterfly over slots */
    float m = -1e30f, z = 0.f;
    for (int c = beg; c < end; c += 64){
        int cn = min(64, end - c);
        int sreg = (lane < cn) ? srcs[c + lane] : 0;
        for (int p = slot; p < cn; p += 16){
            int s = __shfl(sreg, p, 64);
            float v = alS[s*HEADS + head] + ad;
            v = v > 0.f ? v : NEG*v;
            if (v > m){ z = z*__expf(m - v) + 1.f; m = v; }
            else z += __expf(v - m);
        }
    }
    #pragma unroll
    for (int o = 1; o < 16; o <<= 1){
        float m2 = __shfl_xor(m, o, 64);
        float z2 = __shfl_xor(z, o, 64);
        float nm = fmaxf(m, m2);
        z = z*__expf(m - nm) + z2*__expf(m2 - nm);
        m = nm;
    }
    float inv = 1.f / (z + 1e-16f);

    int ch0 = half*512 + lane*8;
    const ushort_t* Hc = H + ch0;
    float c0=0.f,c1=0.f,c2=0.f,c3=0.f,c4=0.f,c5=0.f,c6=0.f,c7=0.f;
    for (int c = beg; c < end; c += 64){
        int cn = min(64, end - c);
        int sreg = (lane < cn) ? srcs[c + lane] : 0;
        int j = 0;
        for (; j + 4 <= cn; j += 4){
            int s0 = __shfl(sreg, j, 64);
            int s1 = __shfl(sreg, j+1, 64);
            int s2 = __shfl(sreg, j+2, 64);
            int s3 = __shfl(sreg, j+3, 64);
            float e0 = alS[s0*HEADS + head];
            float e1 = alS[s1*HEADS + head];
            float e2 = alS[s2*HEADS + head];
            float e3 = alS[s3*HEADS + head];
            uint4 u0 = *(const uint4*)(Hc + (size_t)s0*HT);
            uint4 u1 = *(const uint4*)(Hc + (size_t)s1*HT);
            uint4 u2 = *(const uint4*)(Hc + (size_t)s2*HT);
            uint4 u3 = *(const uint4*)(Hc + (size_t)s3*HT);
            float v0 = e0 + ad; v0 = v0 > 0.f ? v0 : NEG*v0;
            float v1 = e1 + ad; v1 = v1 > 0.f ? v1 : NEG*v1;
            float v2 = e2 + ad; v2 = v2 > 0.f ? v2 : NEG*v2;
            float v3 = e3 + ad; v3 = v3 > 0.f ? v3 : NEG*v3;
            float w0 = __expf(v0 - m) * inv;
            float w1 = __expf(v1 - m) * inv;
            float w2 = __expf(v2 - m) * inv;
            float w3 = __expf(v3 - m) * inv;
            float f0,f1,f2,f3,f4,f5,f6,f7;
            unpack2(u0.x,f0,f1); unpack2(u0.y,f2,f3); unpack2(u0.z,f4,f5); unpack2(u0.w,f6,f7);
            c0+=w0*f0; c1+=w0*f1; c2+=w0*f2; c3+=w0*f3;
            c4+=w0*f4; c5+=w0*f5; c6+=w0*f6; c7+=w0*f7;
            unpack2(u1.x,f0,f1); unpack2(u1.y,f2,f3); unpack2(u1.z,f4,f5); unpack2(u1.w,f6,f7);
            c0+=w1*f0; c1+=w1*f1; c2+=w1*f2; c3+=w1*f3;
            c4+=w1*f4; c5+=w1*f5; c6+=w1*f6; c7+=w1*f7;
            unpack2(u2.x,f0,f1); unpack2(u2.y,f2,f3); unpack2(u2.z,f4,f5); unpack2(u2.w,f6,f7);
            c0+=w2*f0; c1+=w2*f1; c2+=w2*f2; c3+=w2*f3;
            c4+=w2*f4; c5+=w2*f5; c6+=w2*f6; c7+=w2*f7;
            unpack2(u3.x,f0,f1); unpack2(u3.y,f2,f3); unpack2(u3.z,f4,f5); unpack2(u3.w,f6,f7);
            c0+=w3*f0; c1+=w3*f1; c2+=w3*f2; c3+=w3*f3;
            c4+=w3*f4; c5+=w3*f5; c6+=w3*f6; c7+=w3*f7;
        }
        for (; j < cn; j++){
            int s0 = __shfl(sreg, j, 64);
            uint4 u0 = *(const uint4*)(Hc + (size_t)s0*HT);
            float v0 = alS[s0*HEADS + head] + ad;
            v0 = v0 > 0.f ? v0 : NEG*v0;
            float w0 = __expf(v0 - m) * inv;
            float f0,f1,f2,f3,f4,f5,f6,f7;
            unpack2(u0.x,f0,f1); unpack2(u0.y,f2,f3); unpack2(u0.z,f4,f5); unpack2(u0.w,f6,f7);
            c0+=w0*f0; c1+=w0*f1; c2+=w0*f2; c3+=w0*f3;
            c4+=w0*f4; c5+=w0*f5; c6+=w0*f6; c7+=w0*f7;
        }
    }
    float4 b0 = *(const float4*)(bias + ch0);
    float4 b1 = *(const float4*)(bias + ch0 + 4);
    c0 = fmaxf(c0+b0.x, 0.f); c1 = fmaxf(c1+b0.y, 0.f);
    c2 = fmaxf(c2+b0.z, 0.f); c3 = fmaxf(c3+b0.w, 0.f);
    c4 = fmaxf(c4+b1.x, 0.f); c5 = fmaxf(c5+b1.y, 0.f);
    c6 = fmaxf(c6+b1.z, 0.f); c7 = fmaxf(c7+b1.w, 0.f);
    uint4 o;
    o.x = (uint32)f2bf(c0) | ((uint32)f2bf(c1) << 16);
    o.y = (uint32)f2bf(c2) | ((uint32)f2bf(c3) << 16);
    o.z = (uint32)f2bf(c4) | ((uint32)f2bf(c5) << 16);
    o.w = (uint32)f2bf(c6) | ((uint32)f2bf(c7) << 16);
    *(uint4*)(out + (size_t)n*HT + ch0) = o;
}

/* ---------------- layer-2 GEMM: bf16 MFMA, fused attention dots (v2) ----------------
   XCD-swizzled linear grid: XCD x owns bm in [10x,10x+10) for all 8 bn ->
   each A tile served from a single XCD's L2.
   LDS XOR swizzle: quarter q of row r stored at physical slot q^((r>>1)&3);
   reader bank spans become 2-way (free) instead of 8-way. */
__global__ __launch_bounds__(256) void k_gemm2(const ushort_t* __restrict__ A, const ushort_t* __restrict__ BT,
                                               ushort_t* __restrict__ C,
                                               const float* __restrict__ aS, const float* __restrict__ aD,
                                               float* __restrict__ alS, float* __restrict__ alD){
    __shared__ ushort_t lA[128*32];
    __shared__ ushort_t lB[128*32];
    __shared__ float reds[2][64][2];
    int L = blockIdx.x;
    int xcd = L & 7;
    int wi  = L >> 3;
    int bm  = xcd * 10 + (wi >> 3);
    int bn  = wi & 7;
    if (bm >= 79) return;
    int tid = threadIdx.x;
    int lane = tid & 63;
    int wave = tid >> 6;
    int wm = (wave & 1) * 64, wn = (wave >> 1) * 64;
    int lm = lane & 15, kg = lane >> 4;
    int sw = (lm >> 1) & 3;              /* reader swizzle term */
    f32x4 acc[4][4];
    #pragma unroll
    for (int i = 0; i < 4; i++)
        #pragma unroll
        for (int j = 0; j < 4; j++) acc[i][j] = (f32x4)0.0f;

    const int K = 1024;
    int rowA0 = bm * 128, rowB0 = bn * 128;
    for (int k0 = 0; k0 < K; k0 += 32){
        #pragma unroll
        for (int it = 0; it < 2; ++it){
            int s = tid + it*256;
            int r = s >> 2, p = s & 3;
            int qlog = p ^ ((r >> 1) & 3);
            gload_lds16(A  + (size_t)(rowA0 + r)*K + k0 + qlog*8, lA + s*8);
            gload_lds16(BT + (size_t)(rowB0 + r)*K + k0 + qlog*8, lB + s*8);
        }
        __syncthreads();
        bf16x8 af[4], bfr[4];
        int kp = (kg ^ sw) * 8;
        #pragma unroll
        for (int mt = 0; mt < 4; mt++) af[mt]  = *(const bf16x8*)(lA + (wm + mt*16 + lm)*32 + kp);
        #pragma unroll
        for (int nt = 0; nt < 4; nt++) bfr[nt] = *(const bf16x8*)(lB + (wn + nt*16 + lm)*32 + kp);
        #pragma unroll
        for (int mt = 0; mt < 4; mt++)
            #pragma unroll
            for (int nt = 0; nt < 4; nt++)
                acc[mt][nt] = __builtin_amdgcn_mfma_f32_16x16x32_bf16(af[mt], bfr[nt], acc[mt][nt], 0, 0, 0);
        __syncthreads();
    }
    #pragma unroll
    for (int mt = 0; mt < 4; mt++){
        int row_base = bm*128 + wm + mt*16 + kg*4;
        #pragma unroll
        for (int nt = 0; nt < 4; nt++){
            int col = bn*128 + wn + nt*16 + lm;
            #pragma unroll
            for (int r = 0; r < 4; r++){
                int row = row_base + r;
                if (row < N_NODES) C[(size_t)row*HT + col] = f2bf(acc[mt][nt][r]);
            }
        }
    }
    /* fused attention-dot epilogue for head bn */
    float as_l[4], ad_l[4];
    #pragma unroll
    for (int nt = 0; nt < 4; nt++){
        as_l[nt] = aS[bn*128 + wn + nt*16 + lm];
        ad_l[nt] = aD[bn*128 + wn + nt*16 + lm];
    }
    float psA[4][4], pdA[4][4];
    #pragma unroll
    for (int mt = 0; mt < 4; mt++){
        #pragma unroll
        for (int r = 0; r < 4; r++){
            float ps = acc[mt][0][r]*as_l[0] + acc[mt][1][r]*as_l[1]
                     + acc[mt][2][r]*as_l[2] + acc[mt][3][r]*as_l[3];
            float pd = acc[mt][0][r]*ad_l[0] + acc[mt][1][r]*ad_l[1]
                     + acc[mt][2][r]*ad_l[2] + acc[mt][3][r]*ad_l[3];
            #pragma unroll
            for (int o = 1; o < 16; o <<= 1){ ps += __shfl_xor(ps, o, 64); pd += __shfl_xor(pd, o, 64); }
            psA[mt][r] = ps; pdA[mt][r] = pd;
            if (wn == 64 && lm == 0){
                int rl = mt*16 + kg*4 + r;
                reds[wm >> 6][rl][0] = ps;
                reds[wm >> 6][rl][1] = pd;
            }
        }
    }
    __syncthreads();
    if (wn == 0 && lm == 0){
        #pragma unroll
        for (int mt = 0; mt < 4; mt++){
            #pragma unroll
            for (int r = 0; r < 4; r++){
                int rl = mt*16 + kg*4 + r;
                int row = bm*128 + wm + rl;
                if (row < N_NODES){
                    alS[row*HEADS + bn] = psA[mt][r] + reds[wm >> 6][rl][0];
                    alD[row*HEADS + bn] = pdA[mt][r] + reds[wm >> 6][rl][1];
                }
            }
        }
    }
}

/* ---------------- layer-3 GEMM: wave-per-node, W3 in registers ---------------- */
__global__ __launch_bounds__(256) void k_gemm3(const ushort_t* __restrict__ A, const float* __restrict__ W3,
                                               const float* __restrict__ s3,
                                               float* __restrict__ h3, float* __restrict__ al3s, float* __restrict__ al3d){
    int tid = threadIdx.x;
    int lane = tid & 63, wave = tid >> 6;
    int n = blockIdx.x * 4 + wave;
    if (n >= N_NODES) return;
    float4 w3r[16];
    #pragma unroll
    for (int j = 0; j < 16; j++) w3r[j] = ((const float4*)W3)[lane*16 + j];
    const uint4* ap = (const uint4*)(A + (size_t)n*HT + lane*16);
    uint4 u0 = ap[0], u1 = ap[1];
    uint32 uu[8] = {u0.x,u0.y,u0.z,u0.w,u1.x,u1.y,u1.z,u1.w};
    float acc0=0.f, acc1=0.f, acc2=0.f, acc3=0.f;
    #pragma unroll
    for (int p = 0; p < 8; p++){
        float lo, hi;
        unpack2(uu[p], lo, hi);
        float4 wl = w3r[p*2], wh = w3r[p*2+1];
        acc0 += lo*wl.x + hi*wh.x;
        acc1 += lo*wl.y + hi*wh.y;
        acc2 += lo*wl.z + hi*wh.z;
        acc3 += lo*wl.w + hi*wh.w;
    }
    #pragma unroll
    for (int o = 32; o; o >>= 1){
        acc0 += __shfl_xor(acc0, o, 64); acc1 += __shfl_xor(acc1, o, 64);
        acc2 += __shfl_xor(acc2, o, 64); acc3 += __shfl_xor(acc3, o, 64);
    }
    if (lane == 0){
        *(float4*)(h3 + n*4) = make_float4(acc0, acc1, acc2, acc3);
        al3s[n] = acc0*s3[0] + acc1*s3[1] + acc2*s3[2] + acc3*s3[3];
        al3d[n] = acc0*s3[16] + acc1*s3[17] + acc2*s3[18] + acc3*s3[19];
    }
}

/* ---------------- layer-3 attention aggregate: wave-per-node ---------------- */
__global__ __launch_bounds__(256) void k_gat_agg3(const float* __restrict__ h3, const float* __restrict__ al3s,
                                                  const float* __restrict__ al3d, const int* __restrict__ offs,
                                                  const int* __restrict__ srcs, const float* __restrict__ b3,
                                                  const int* __restrict__ flags, void* __restrict__ out){
    int tid = threadIdx.x;
    int l = tid & 63, wave = tid >> 6;
    int n = blockIdx.x * 4 + wave;
    if (n >= N_NODES) return;
    int beg = offs[n], end = offs[n+1];
    float ad = al3d[n];
    float m = -1e30f;
    for (int e = beg + l; e < end; e += 64){
        float v = al3s[srcs[e]] + ad; v = v > 0.f ? v : NEG*v;
        m = fmaxf(m, v);
    }
    #pragma unroll
    for (int o = 32; o; o >>= 1) m = fmaxf(m, __shfl_xor(m, o, 64));
    float z = 0.f;
    for (int e = beg + l; e < end; e += 64){
        float v = al3s[srcs[e]] + ad; v = v > 0.f ? v : NEG*v;
        z += __expf(v - m);
    }
    #pragma unroll
    for (int o = 32; o; o >>= 1) z += __shfl_xor(z, o, 64);
    float inv = 1.f / (z + 1e-16f);
    float a0=0.f, a1=0.f, a2=0.f, a3=0.f;
    for (int e = beg + l; e < end; e += 64){
        int s = srcs[e];
        float v = al3s[s] + ad; v = v > 0.f ? v : NEG*v;
        float w = __expf(v - m) * inv;
        float4 hv = *(const float4*)(h3 + s*4);
        a0 += w*hv.x; a1 += w*hv.y; a2 += w*hv.z; a3 += w*hv.w;
    }
    #pragma unroll
    for (int o = 32; o; o >>= 1){
        a0 += __shfl_xor(a0, o, 64); a1 += __shfl_xor(a1, o, 64);
        a2 += __shfl_xor(a2, o, 64); a3 += __shfl_xor(a3, o, 64);
    }
    if (l == 0){
        float r0 = fmaxf(a0 + b3[0], 0.f);
        float r1 = fmaxf(a1 + b3[1], 0.f);
        float r2 = fmaxf(a2 + b3[2], 0.f);
        float r3 = fmaxf(a3 + b3[3], 0.f);
        if (flags[1]){
            float* o4 = (float*)out;
            o4[n*4+0]=r0; o4[n*4+1]=r1; o4[n*4+2]=r2; o4[n*4+3]=r3;
        } else {
            ushort_t* o2 = (ushort_t*)out;
            o2[n*4+0]=f2bf(r0); o2[n*4+1]=f2bf(r1); o2[n*4+2]=f2bf(r2); o2[n*4+3]=f2bf(r3);
        }
    }
}

extern "C" void kernel_launch(void* const* d_in, const int* in_sizes, int n_in,
                              void* d_out, int out_size, void* d_ws, size_t ws_size,
                              hipStream_t stream){
    const void* x   = d_in[0];
    const void* ei  = d_in[1];
    const void* W1  = d_in[2];
    const void* as1 = d_in[3];
    const void* ad1 = d_in[4];
    const void* b1  = d_in[5];
    const void* W2  = d_in[6];
    const void* as2 = d_in[7];
    const void* ad2 = d_in[8];
    const void* b2  = d_in[9];
    const void* W3  = d_in[10];
    const void* as3 = d_in[11];
    const void* ad3 = d_in[12];
    const void* b3  = d_in[13];

    char* ws = (char*)d_ws;
    int* flags     = (int*)(ws + O_FLAG);
    int* srcA      = (int*)(ws + O_SRC);
    int* dstA      = (int*)(ws + O_DST);
    int* counts    = (int*)(ws + O_COUNTS);
    int* offs      = (int*)(ws + O_OFFS);
    int* cursors   = (int*)(ws + O_CURS);
    int* ssort     = (int*)(ws + O_SSORT);
    float* alS     = (float*)(ws + O_ALS);
    float* alD     = (float*)(ws + O_ALD);
    float* al3s    = (float*)(ws + O_AL3S);
    float* al3d    = (float*)(ws + O_AL3D);
    float* h3      = (float*)(ws + O_H3);
    float* xF      = (float*)(ws + O_XF);
    float* W1F     = (float*)(ws + O_W1F);
    float* wvecF   = (float*)(ws + O_AS1F);
    float* W3F     = (float*)(ws + O_W3F);
    float* s3F     = (float*)(ws + O_S3F);
    ushort_t* W2T  = (ushort_t*)(ws + O_W2T);
    ushort_t* bufA = (ushort_t*)(ws + O_BUFA);
    ushort_t* bufB = (ushort_t*)(ws + O_BUFB);

    const int EB = (ET + 255) / 256;

    CvtArgs ca;
    ca.src[0]=x;   ca.dst[0]=xF;            ca.n[0]=140000;
    ca.src[1]=W1;  ca.dst[1]=W1F;           ca.n[1]=14336;
    ca.src[2]=as1; ca.dst[2]=wvecF+0*1024;  ca.n[2]=1024;
    ca.src[3]=ad1; ca.dst[3]=wvecF+1*1024;  ca.n[3]=1024;
    ca.src[4]=b1;  ca.dst[4]=wvecF+2*1024;  ca.n[4]=1024;
    ca.src[5]=as2; ca.dst[5]=wvecF+3*1024;  ca.n[5]=1024;
    ca.src[6]=ad2; ca.dst[6]=wvecF+4*1024;  ca.n[6]=1024;
    ca.src[7]=b2;  ca.dst[7]=wvecF+5*1024;  ca.n[7]=1024;
    ca.src[8]=W3;  ca.dst[8]=W3F;           ca.n[8]=4096;
    ca.src[9]=as3; ca.dst[9]=s3F+0;         ca.n[9]=4;
    ca.src[10]=ad3; ca.dst[10]=s3F+16;      ca.n[10]=4;
    ca.src[11]=b3;  ca.dst[11]=s3F+32;      ca.n[11]=4;

    k_setup<<<dim3(1024, 14), 256, 0, stream>>>(ca, W2, (const uint32*)W1, (const int*)ei,
                                                counts, W2T, flags);
    k_extract_hist<<<EB, 256, 0, stream>>>(ei, flags, srcA, dstA, counts);
    k_scan<<<1, 1024, 0, stream>>>(counts, offs, cursors, N_NODES);
    k_scatter<<<EB, 256, 0, stream>>>(srcA, dstA, cursors, ssort);

    /* layer 1 (gemm + dots fused) */
    k_gemm1f<<<512, 256, 0, stream>>>(xF, W1F, wvecF+0*1024, wvecF+1*1024, bufA, alS, alD);
    k_gat_agg<<<5000, 256, 0, stream>>>(bufA, alS, alD, offs, ssort, wvecF+2*1024, bufB);

    /* layer 2 (gemm + dots fused, XCD-swizzled linear grid) */
    k_gemm2<<<640, 256, 0, stream>>>(bufB, W2T, bufA, wvecF+3*1024, wvecF+4*1024, alS, alD);
    k_gat_agg<<<5000, 256, 0, stream>>>(bufA, alS, alD, offs, ssort, wvecF+5*1024, bufB);

    /* layer 3 */
    k_gemm3<<<2500, 256, 0, stream>>>(bufB, W3F, s3F, h3, al3s, al3d);
    k_gat_agg3<<<2500, 256, 0, stream>>>(h3, al3s, al3d, offs, ssort, s3F+32, flags, d_out);
}